// Round 3
// baseline (108.702 us; speedup 1.0000x reference)
//
#include <hip/hip_runtime.h>

#define H 512
#define W 512
#define RH 508
#define RW 508
#define OH 510
#define OW 510

// One block: 4 output rows x 256 cols for one (b,g). 256 threads, 4 px/thread.
// No LDS: x windows come straight from L1/L2 (x is 4 MB, cache-resident).
// Stores: one float4 per channel per thread -> per-lane-contiguous 1 KB per
// wave instruction, full cache-line coverage (fixes partial-line RMW).

__global__ __launch_bounds__(256) void morph2d_fused(
    const float* __restrict__ x,      // (4,512,512)
    const float* __restrict__ wgt,    // (16,3,3) binary
    float* __restrict__ out)          // (4,64,510,510)
{
    const int tid   = threadIdx.x;
    const int bg    = blockIdx.y;          // b*16+g
    const int b     = bg >> 4;
    const int g     = bg & 15;
    const int half  = blockIdx.x & 1;
    const int strip = blockIdx.x >> 1;     // 0..127
    const int r     = strip * 4 + (tid >> 6);
    const int c     = half * 256 + (tid & 63) * 4;

    // uniform binary-weight bitmask
    int wm = 0;
#pragma unroll
    for (int t = 0; t < 9; ++t) wm |= (wgt[g * 9 + t] > 0.5f) ? (1 << t) : 0;
    wm = __builtin_amdgcn_readfirstlane(wm);

    float dv[4], ev[4], ov[4], cl[4];
#pragma unroll
    for (int p = 0; p < 4; ++p) dv[p] = ev[p] = ov[p] = cl[p] = 0.0f;

    if (r < RH && c < RW) {
        // x window 5 rows x 8 cols, all in-bounds for live threads (r<=507,c<=504)
        const float* xb = x + ((size_t)b * H + r) * W + c;
        float xr[5][8];
#pragma unroll
        for (int i = 0; i < 5; ++i) {
            *(float4*)&xr[i][0] = *(const float4*)(xb + i * W);
            *(float4*)&xr[i][4] = *(const float4*)(xb + i * W + 4);
        }

        // ---- pass 1: dil/ero on the 3x6 site block [r..r+2][c..c+5] ----
        float d[3][6], e[3][6];
#pragma unroll
        for (int si = 0; si < 3; ++si)
#pragma unroll
            for (int sc = 0; sc < 6; ++sc) { d[si][sc] = 0.0f; e[si][sc] = INFINITY; }

#pragma unroll
        for (int T = 0; T < 9; ++T) {
            const int ti = T / 3, tj = T % 3;
            if (wm & (1 << T)) {       // w=1: dil |x|, ero |x+1|
#pragma unroll
                for (int si = 0; si < 3; ++si)
#pragma unroll
                    for (int sc = 0; sc < 6; ++sc) {
                        float xv = xr[si + ti][sc + tj];
                        d[si][sc] = fmaxf(d[si][sc], fabsf(xv));
                        e[si][sc] = fminf(e[si][sc], fabsf(xv + 1.0f));
                    }
            } else {                   // w=0: dil |x*0|=0 (covered by init), ero |x|
#pragma unroll
                for (int si = 0; si < 3; ++si)
#pragma unroll
                    for (int sc = 0; sc < 6; ++sc)
                        e[si][sc] = fminf(e[si][sc], fabsf(xr[si + ti][sc + tj]));
            }
        }
        // reference pads dil/ero with zeros beyond (RH,RW)
#pragma unroll
        for (int si = 0; si < 3; ++si)
#pragma unroll
            for (int sc = 0; sc < 6; ++sc) {
                bool v = (r + si < RH) && (c + sc < RW);
                if (!v) { d[si][sc] = 0.0f; e[si][sc] = 0.0f; }
            }

        // ---- pass 2: opening/closing ----
        float o[4], m1[4], m0[4];
#pragma unroll
        for (int p = 0; p < 4; ++p) { o[p] = 0.0f; m1[p] = INFINITY; m0[p] = INFINITY; }
#pragma unroll
        for (int T = 0; T < 9; ++T) {
            const int ti = T / 3, tj = T % 3;
            if (wm & (1 << T)) {
#pragma unroll
                for (int p = 0; p < 4; ++p) {
                    o[p]  = fmaxf(o[p],  e[ti][p + tj]);   // e >= 0, |e*1|=e; w=0 taps give 0 = init
                    m1[p] = fminf(m1[p], d[ti][p + tj]);   // d >= 0, |d+1| = d+1, hoisted
                }
            } else {
#pragma unroll
                for (int p = 0; p < 4; ++p)
                    m0[p] = fminf(m0[p], d[ti][p + tj]);   // |d+0| = d
            }
        }
#pragma unroll
        for (int p = 0; p < 4; ++p) {
            dv[p] = d[0][p];
            ev[p] = e[0][p];
            ov[p] = o[p];
            cl[p] = fminf(m1[p] + 1.0f, m0[p]);            // min over taps of |dil + w|
        }
    }

    // ---- stores: one float4 per channel, per-lane contiguous ----
    if (r < OH) {
        const size_t plane = (size_t)OH * OW;
        float* ob = out + (size_t)bg * 4 * plane + (size_t)r * OW + c;
        float4 vals[4];
        vals[0] = make_float4(dv[0], dv[1], dv[2], dv[3]);
        vals[1] = make_float4(ev[0], ev[1], ev[2], ev[3]);
        vals[2] = make_float4(ov[0], ov[1], ov[2], ov[3]);
        vals[3] = make_float4(cl[0], cl[1], cl[2], cl[3]);
        if (c + 3 < OW) {
#pragma unroll
            for (int ch = 0; ch < 4; ++ch)
                __builtin_memcpy(ob + (size_t)ch * plane, &vals[ch], 16);  // rows may be 8B-aligned
        } else if (c < OW) {           // c == 508: last two columns (always pad zeros)
#pragma unroll
            for (int ch = 0; ch < 4; ++ch) {
                float2 v2 = make_float2(vals[ch].x, vals[ch].y);
                __builtin_memcpy(ob + (size_t)ch * plane, &v2, 8);
            }
        }
    }
}

extern "C" void kernel_launch(void* const* d_in, const int* in_sizes, int n_in,
                              void* d_out, int out_size, void* d_ws, size_t ws_size,
                              hipStream_t stream) {
    const float* x = (const float*)d_in[0];   // (4,1,512,512) f32
    const float* w = (const float*)d_in[1];   // (16,1,3,3)  f32
    float* out = (float*)d_out;               // (4,64,510,510) f32
    dim3 grid(2 * 128, 64);   // (colhalf, strip) x (b,g)
    morph2d_fused<<<grid, 256, 0, stream>>>(x, w, out);
}

// Round 5
// 80.374 us; speedup vs baseline: 1.3525x; 1.3525x over previous
//
#include <hip/hip_runtime.h>

#define H 512
#define W 512
#define RH 508
#define RW 508
#define OH 510
#define OW 510
#define CHUNK 32          // output rows per block
#define NCHUNK 16         // 16*32 = 512 >= 510
#define ITERS (CHUNK/2)   // 2 rows per iteration

// Rolling-row fused morphology. Block = one (b,g) x one 32-row full-width chunk.
// Per iteration: compute dil/ero rows r+2,r+3 (store them + push to LDS ring),
// barrier, compute opening/closing rows r,r+1 from the ring (store them).
// All 4 channel streams advance 2 dense rows per iteration -> continuous,
// linear, full-coverage write streams (fillBuffer-shaped duty cycle).

__global__ __launch_bounds__(256) void morph2d_roll(
    const float* __restrict__ x,      // (4,512,512)
    const float* __restrict__ wgt,    // (16,3,3) binary
    float* __restrict__ out)          // (4,64,510,510)
{
    __shared__ float2 dering[8][512];   // 32 KB ring of (dil,ero) rows

    const int tid   = threadIdx.x;
    const int bg    = blockIdx.x & 63;          // b*16+g
    const int chunk = blockIdx.x >> 6;          // 0..15
    const int b     = bg >> 4;
    const int g     = bg & 15;
    const int L     = chunk * CHUNK;

    const int lane  = tid & 127;      // column group: cols 4*lane..4*lane+3
    const int rsel  = tid >> 7;       // row of the pair (uniform per wave)
    const int c4    = lane * 4;       // 0..508

    // uniform binary weight mask
    int wm = 0;
#pragma unroll
    for (int t = 0; t < 9; ++t) wm |= (wgt[g * 9 + t] > 0.5f) ? (1 << t) : 0;
    wm = __builtin_amdgcn_readfirstlane(wm);

    const float*  xb    = x + (size_t)b * (H * W);
    const size_t  plane = (size_t)OH * OW;
    float*        outbg = out + (size_t)bg * 4 * plane;

    // compute dil/ero at (deR, c4..c4+3); caller guarantees deR<RH, lane<127
    auto compute_de = [&](int deR, float dd[4], float ee[4]) {
        float xr[3][8];
#pragma unroll
        for (int i = 0; i < 3; ++i) {
            const float* p = xb + (size_t)(deR + i) * W + c4;
            *(float4*)&xr[i][0] = *(const float4*)p;
            *(float4*)&xr[i][4] = *(const float4*)(p + 4);
        }
#pragma unroll
        for (int p = 0; p < 4; ++p) { dd[p] = 0.f; ee[p] = INFINITY; }
#pragma unroll
        for (int T = 0; T < 9; ++T) {
            const int ti = T / 3, tj = T % 3;
            if (wm & (1 << T)) {
#pragma unroll
                for (int p = 0; p < 4; ++p) {
                    float xv = xr[ti][p + tj];
                    dd[p] = fmaxf(dd[p], fabsf(xv));         // |x*1|
                    ee[p] = fminf(ee[p], fabsf(xv + 1.0f));  // |x+1|
                }
            } else {
#pragma unroll
                for (int p = 0; p < 4; ++p)
                    ee[p] = fminf(ee[p], fabsf(xr[ti][p + tj]));  // |x+0|
            }
        }
    };

    // store one channel-row fragment (lane<127: float4; lane==127: float2 @508)
    auto store_row = [&](int ch, int row, const float v[4]) {
        float* p = outbg + (size_t)ch * plane + (size_t)row * OW + c4;
        if (lane < 127) {
            __builtin_memcpy(p, v, 16);
        } else {
            float2 z = make_float2(v[0], v[1]);
            __builtin_memcpy(p, &z, 8);
        }
    };

    auto ring_write = [&](int row, const float dd[4], const float ee[4]) {
        float2* rp = &dering[row & 7][c4];
        float4 w0, w1;
        ((float2*)&w0)[0] = make_float2(dd[0], ee[0]);
        ((float2*)&w0)[1] = make_float2(dd[1], ee[1]);
        ((float2*)&w1)[0] = make_float2(dd[2], ee[2]);
        ((float2*)&w1)[1] = make_float2(dd[3], ee[3]);
        *(float4*)rp       = w0;
        *(float4*)(rp + 2) = w1;
    };

    // ---- prologue: de rows L, L+1 into ring (chunk 0 also stores them) ----
    {
        const int deR = L + rsel;
        float dd[4] = {0, 0, 0, 0}, ee[4] = {0, 0, 0, 0};
        if (lane < 127 && deR < RH) compute_de(deR, dd, ee);
        ring_write(deR, dd, ee);
        if (chunk == 0) { store_row(0, deR, dd); store_row(1, deR, ee); }
    }
    // visibility of prologue ring writes is covered by iteration 0's barrier

#pragma unroll 2
    for (int i = 0; i < ITERS; ++i) {
        // ---- de phase: rows L+2i+2, L+2i+3 ----
        const int deR = L + 2 * i + 2 + rsel;
        float dd[4] = {0, 0, 0, 0}, ee[4] = {0, 0, 0, 0};
        if (lane < 127 && deR < RH) compute_de(deR, dd, ee);
        if (deR < OH) {
            ring_write(deR, dd, ee);          // rows 508/509 written as zeros
            store_row(0, deR, dd);
            store_row(1, deR, ee);
        }
        __syncthreads();

        // ---- oc phase: rows L+2i, L+2i+1 ----
        const int ocR = L + 2 * i + rsel;
        float oo[4] = {0, 0, 0, 0}, cc[4] = {0, 0, 0, 0};
        if (lane < 127 && ocR < RH) {
            float2 win[3][6];
#pragma unroll
            for (int k = 0; k < 3; ++k) {
                const float2* rp = &dering[(ocR + k) & 7][c4];
                *(float4*)&win[k][0] = *(const float4*)rp;        // cols c4,   c4+1
                *(float4*)&win[k][2] = *(const float4*)(rp + 2);  // cols c4+2, c4+3
                *(float4*)&win[k][4] = *(const float4*)(rp + 4);  // cols c4+4, c4+5  (BUGFIX: was float2)
            }
            float m1[4] = {INFINITY, INFINITY, INFINITY, INFINITY};
            float m0[4] = {INFINITY, INFINITY, INFINITY, INFINITY};
#pragma unroll
            for (int T = 0; T < 9; ++T) {
                const int ti = T / 3, tj = T % 3;
                if (wm & (1 << T)) {
#pragma unroll
                    for (int p = 0; p < 4; ++p) {
                        oo[p] = fmaxf(oo[p], win[ti][p + tj].y);  // ero>=0
                        m1[p] = fminf(m1[p], win[ti][p + tj].x);  // min dil, w=1
                    }
                } else {
#pragma unroll
                    for (int p = 0; p < 4; ++p)
                        m0[p] = fminf(m0[p], win[ti][p + tj].x);  // min dil, w=0
                }
            }
#pragma unroll
            for (int p = 0; p < 4; ++p) cc[p] = fminf(m1[p] + 1.0f, m0[p]);
        }
        if (ocR < OH) { store_row(2, ocR, oo); store_row(3, ocR, cc); }
        // no second barrier: next iter's ring-write slots (2i+4,2i+5)&7 are
        // disjoint from this oc read set (2i..2i+3)&7; slot reuse is >=2
        // barriers away.
    }
}

extern "C" void kernel_launch(void* const* d_in, const int* in_sizes, int n_in,
                              void* d_out, int out_size, void* d_ws, size_t ws_size,
                              hipStream_t stream) {
    const float* x = (const float*)d_in[0];   // (4,1,512,512) f32
    const float* w = (const float*)d_in[1];   // (16,1,3,3)  f32
    float* out = (float*)d_out;               // (4,64,510,510) f32
    dim3 grid(64 * NCHUNK);                   // 1024 blocks: (bg, chunk)
    morph2d_roll<<<grid, 256, 0, stream>>>(x, w, out);
}